// Round 23
// baseline (120.509 us; speedup 1.0000x reference)
//
#include <hip/hip_runtime.h>
#include <hip/hip_bf16.h>
#include <cstdint>

#define TT 2048
#define HD 64
#define NH 16
#define CDIM 1024
#define N3 3072
#define BT 4096
#define QSCALE 0.18033688011112042f  // 0.125 * log2(e)

using bf16 = __hip_bfloat16;
typedef __attribute__((ext_vector_type(4))) float f32x4;
typedef __attribute__((ext_vector_type(8))) short short8;
typedef __attribute__((ext_vector_type(8))) __bf16 bf16x8v;

__device__ __forceinline__ short f2bbits(float f) {
  __hip_bfloat16 h = __float2bfloat16(f);
  return __builtin_bit_cast(short, h);
}

__device__ __forceinline__ f32x4 mfma_bf16(short8 a, short8 b, f32x4 c) {
  return __builtin_amdgcn_mfma_f32_16x16x32_bf16(
      __builtin_bit_cast(bf16x8v, a), __builtin_bit_cast(bf16x8v, b), c, 0, 0, 0);
}

__device__ __forceinline__ void gll16(const void* g, void* l) {
  __builtin_amdgcn_global_load_lds(
      (const __attribute__((address_space(1))) void*)g,
      (__attribute__((address_space(3))) void*)l, 16, 0, 0);
}

// v_exp_f32 computes 2^x
__device__ __forceinline__ float exp2_fast(float x) {
  float r;
  asm("v_exp_f32 %0, %1" : "=v"(r) : "v"(x));
  return r;
}

// pack two f32 -> one u32 of 2 bf16 (lo = first arg), RNE
__device__ __forceinline__ uint32_t pkbf16(float lo, float hi) {
  uint32_t lw = (uint32_t)(uint16_t)f2bbits(lo);
  uint32_t hw = (uint32_t)(uint16_t)f2bbits(hi);
  return (hw << 16) | lw;
}

// ---------------- fused prep kernel ----------------
// blocks [0,2048): cvt x -> xb
// blocks [2048,5120): transpose Wqkv [1024][3072] -> WqkvT bf16
// blocks [5120,6144): transpose Wout [1024][1024] -> WoutT bf16
// blocks [6144,6400): rope cos/sin table (float2 interleaved)

__device__ __forceinline__ void transpose_body(const float* __restrict__ in,
                                               bf16* __restrict__ out, int R, int C,
                                               int bx, int by, int tx, int ty,
                                               float (*tile)[33]) {
  int c0 = bx * 32, r0 = by * 32;
#pragma unroll
  for (int i = 0; i < 32; i += 8)
    tile[ty + i][tx] = in[(size_t)(r0 + ty + i) * C + c0 + tx];
  __syncthreads();
#pragma unroll
  for (int i = 0; i < 32; i += 8)
    out[(size_t)(c0 + ty + i) * R + r0 + tx] = __float2bfloat16(tile[tx][ty + i]);
}

__global__ __launch_bounds__(256) void prep(const float* __restrict__ x, bf16* __restrict__ xb,
                                            const float* __restrict__ Wqkv, bf16* __restrict__ WqkvT,
                                            const float* __restrict__ Wout, bf16* __restrict__ WoutT,
                                            float2* __restrict__ cs) {
  __shared__ float tile[32][33];
  int bid = blockIdx.x, tid = threadIdx.x;
  if (bid < 2048) {
    int idx = (bid * 256 + tid) * 8;
    float4 a = *(const float4*)(x + idx);
    float4 b = *(const float4*)(x + idx + 4);
    short8 o;
    o[0] = f2bbits(a.x); o[1] = f2bbits(a.y); o[2] = f2bbits(a.z); o[3] = f2bbits(a.w);
    o[4] = f2bbits(b.x); o[5] = f2bbits(b.y); o[6] = f2bbits(b.z); o[7] = f2bbits(b.w);
    *(short8*)(xb + idx) = o;
  } else if (bid < 5120) {
    int id = bid - 2048;
    transpose_body(Wqkv, WqkvT, CDIM, N3, id % 96, id / 96, tid & 31, tid >> 5, tile);
  } else if (bid < 6144) {
    int id = bid - 5120;
    transpose_body(Wout, WoutT, CDIM, CDIM, id & 31, id >> 5, tid & 31, tid >> 5, tile);
  } else {
    int idx = (bid - 6144) * 256 + tid;  // t*32 + i
    int t = idx >> 5, i = idx & 31;
    double inv = exp(-(double)i / 32.0 * log(10000.0));
    double a = (double)t * inv;
    float2 v; v.x = (float)cos(a); v.y = (float)sin(a);
    cs[idx] = v;
  }
}

// ---------------- GEMM core: C[128x128] = A[128xK] * Bt[128xK]^T ----------------
// BK=64, XOR-swizzled LDS (pre-swizzled global source chunks, linear gll16 dest,
// swizzled ds_read). 256 threads, 4 waves (2x2 of 64x64 sub-tiles).

__device__ __forceinline__ void gemm_core(const bf16* __restrict__ A, const bf16* __restrict__ Bt,
                                          int K, int m0, int n0, f32x4 acc[4][4],
                                          bf16* As, bf16* Bs) {
  int tid = threadIdx.x;
  int w = tid >> 6, l = tid & 63;
  int wm = (w >> 1) * 64, wn = (w & 1) * 64;
  for (int kt = 0; kt < K; kt += 64) {
#pragma unroll
    for (int it = 0; it < 4; ++it) {
      int ci = it * 256 + tid;            // 0..1023 chunk index (16B chunks)
      int r = ci >> 3, cc = ci & 7;
      int sc = cc ^ (r & 7);              // pre-swizzled source chunk
      gll16(A + (size_t)(m0 + r) * K + kt + sc * 8, As + (it * 256 + w * 64) * 8);
      gll16(Bt + (size_t)(n0 + r) * K + kt + sc * 8, Bs + (it * 256 + w * 64) * 8);
    }
    __syncthreads();
#pragma unroll
    for (int c = 0; c < 2; ++c) {
      short8 af[4], bfr[4];
#pragma unroll
      for (int i = 0; i < 4; ++i) {
        int row = wm + i * 16 + (l & 15);
        int colE = c * 32 + (l >> 4) * 8;
        af[i] = *(const short8*)(As + row * 64 + (colE ^ ((row & 7) << 3)));
      }
#pragma unroll
      for (int j = 0; j < 4; ++j) {
        int row = wn + j * 16 + (l & 15);
        int colE = c * 32 + (l >> 4) * 8;
        bfr[j] = *(const short8*)(Bs + row * 64 + (colE ^ ((row & 7) << 3)));
      }
#pragma unroll
      for (int i = 0; i < 4; ++i)
#pragma unroll
        for (int j = 0; j < 4; ++j)
          acc[i][j] = mfma_bf16(af[i], bfr[j], acc[i][j]);
    }
    __syncthreads();
  }
}

// QKV GEMM: x[4096][1024] @ Wqkv, tile 64x128 (BM=64), grid (24,64) = 1536 blocks.
// Q/K: RoPE fused (pair (d,d+32) in-lane), Q pre-scaled by QSCALE.
// V: written DIRECTLY TRANSPOSED to VT [bh][64 d][T t] via LDS bounce (64d x 64t).
__global__ __launch_bounds__(256) void qkv_gemm(const bf16* __restrict__ xb,
                                                const bf16* __restrict__ WqkvT,
                                                const float2* __restrict__ cs,
                                                bf16* __restrict__ Qb, bf16* __restrict__ Kb,
                                                bf16* __restrict__ VTb) {
  __shared__ bf16 Sh[64 * 64 + 128 * 64];   // As (8KB) | Bs (16KB); Sh reused as V bounce
  bf16* As = Sh;
  bf16* Bs = Sh + 64 * 64;
  int m0 = blockIdx.y * 64, n0 = blockIdx.x * 128;
  int tid = threadIdx.x, w = tid >> 6, l = tid & 63;
  int wm = (w >> 1) * 32, wn = (w & 1) * 64;
  f32x4 acc[2][4] = {};

  for (int kt = 0; kt < CDIM; kt += 64) {
    // stage A tile 64x64 (512 chunks) + B tile 128x64 (1024 chunks)
#pragma unroll
    for (int it = 0; it < 2; ++it) {
      int ci = it * 256 + tid, r = ci >> 3, cc = ci & 7;
      int sc = cc ^ (r & 7);
      gll16(xb + (size_t)(m0 + r) * CDIM + kt + sc * 8, As + (it * 256 + w * 64) * 8);
    }
#pragma unroll
    for (int it = 0; it < 4; ++it) {
      int ci = it * 256 + tid, r = ci >> 3, cc = ci & 7;
      int sc = cc ^ (r & 7);
      gll16(WqkvT + (size_t)(n0 + r) * CDIM + kt + sc * 8, Bs + (it * 256 + w * 64) * 8);
    }
    __syncthreads();
#pragma unroll
    for (int c = 0; c < 2; ++c) {
      short8 af[2], bfr[4];
#pragma unroll
      for (int i = 0; i < 2; ++i) {
        int row = wm + i * 16 + (l & 15);
        int colE = c * 32 + (l >> 4) * 8;
        af[i] = *(const short8*)(As + row * 64 + (colE ^ ((row & 7) << 3)));
      }
#pragma unroll
      for (int j = 0; j < 4; ++j) {
        int row = wn + j * 16 + (l & 15);
        int colE = c * 32 + (l >> 4) * 8;
        bfr[j] = *(const short8*)(Bs + row * 64 + (colE ^ ((row & 7) << 3)));
      }
#pragma unroll
      for (int i = 0; i < 2; ++i)
#pragma unroll
        for (int j = 0; j < 4; ++j)
          acc[i][j] = mfma_bf16(af[i], bfr[j], acc[i][j]);
    }
    __syncthreads();
  }

  int which = n0 >> 10;                       // 0=Q 1=K 2=V
  if (which < 2) {
    int h = ((n0 + wn) & 1023) >> 6;          // head (wn is 0 or 64 -> full head per wave)
    bf16* Out = which == 0 ? Qb : Kb;
    float sc = (which == 0) ? QSCALE : 1.0f;
    // RoPE: pair (d, d+32) lives in (acc[i][j], acc[i][j+2]) of the same lane
#pragma unroll
    for (int i = 0; i < 2; ++i)
#pragma unroll
      for (int r = 0; r < 4; ++r) {
        int m = m0 + wm + i * 16 + (l >> 4) * 4 + r;
        int b = m >> 11, t = m & 2047;
        size_t base = (((size_t)(b * NH + h)) * TT + t) * HD;
#pragma unroll
        for (int j = 0; j < 2; ++j) {
          int ii = j * 16 + (l & 15);         // d in [0,32)
          float2 v = cs[t * 32 + ii];
          float x1 = acc[i][j][r], x2 = acc[i][j + 2][r];
          Out[base + ii]      = __float2bfloat16((x1 * v.x - x2 * v.y) * sc);
          Out[base + ii + 32] = __float2bfloat16((x2 * v.x + x1 * v.y) * sc);
        }
      }
  } else {
    // V: transpose through LDS bounce [64 dloc][pitch 72] (64 t), then coalesced
    // stores to VTb[bh][d][t0..t0+63]. Two passes, one head (64 d) each.
    const int BP = 72;                        // 16B-aligned pitch (144B rows)
    int hb = (n0 & 1023) >> 6;                // first of the 2 heads in this block
    int b = m0 >> 11, t0 = m0 & 2047;
#pragma unroll
    for (int p = 0; p < 2; ++p) {
      if ((w & 1) == p) {                     // waves whose wn == 64*p hold this head
#pragma unroll
        for (int i = 0; i < 2; ++i)
#pragma unroll
          for (int j = 0; j < 4; ++j)
#pragma unroll
            for (int r = 0; r < 4; ++r) {
              int dloc = j * 16 + (l & 15);
              int mloc = wm + i * 16 + (l >> 4) * 4 + r;
              Sh[dloc * BP + mloc] = __float2bfloat16(acc[i][j][r]);
            }
      }
      __syncthreads();
      {
        int dloc = tid >> 2, tch = (tid & 3) * 16;
        bf16* dst = VTb + (((size_t)(b * NH + hb + p)) * HD + dloc) * TT + t0 + tch;
        const bf16* srcb = Sh + dloc * BP + tch;
#pragma unroll
        for (int k2 = 0; k2 < 2; ++k2)
          *(uint4*)(dst + k2 * 8) = *(const uint4*)(srcb + k2 * 8);
      }
      __syncthreads();
    }
  }
}

// Out GEMM: O[4096][1024] @ Wout + bout -> out fp32.
// Tile 64x128 (BM=64), grid (8,64) = 512 blocks = 2 blocks/CU.
__global__ __launch_bounds__(256) void out_gemm(const bf16* __restrict__ Ob,
                                                const bf16* __restrict__ WoutT,
                                                const float* __restrict__ bout,
                                                float* __restrict__ out) {
  __shared__ bf16 As[64 * 64];    // 8KB
  __shared__ bf16 Bs[128 * 64];   // 16KB
  int m0 = blockIdx.y * 64, n0 = blockIdx.x * 128;
  int tid = threadIdx.x, w = tid >> 6, l = tid & 63;
  int wm = (w >> 1) * 32, wn = (w & 1) * 64;
  f32x4 acc[2][4] = {};

  for (int kt = 0; kt < CDIM; kt += 64) {
#pragma unroll
    for (int it = 0; it < 2; ++it) {
      int ci = it * 256 + tid, r = ci >> 3, cc = ci & 7;
      int sc = cc ^ (r & 7);
      gll16(Ob + (size_t)(m0 + r) * CDIM + kt + sc * 8, As + (it * 256 + w * 64) * 8);
    }
#pragma unroll
    for (int it = 0; it < 4; ++it) {
      int ci = it * 256 + tid, r = ci >> 3, cc = ci & 7;
      int sc = cc ^ (r & 7);
      gll16(WoutT + (size_t)(n0 + r) * CDIM + kt + sc * 8, Bs + (it * 256 + w * 64) * 8);
    }
    __syncthreads();
#pragma unroll
    for (int c = 0; c < 2; ++c) {
      short8 af[2], bfr[4];
#pragma unroll
      for (int i = 0; i < 2; ++i) {
        int row = wm + i * 16 + (l & 15);
        int colE = c * 32 + (l >> 4) * 8;
        af[i] = *(const short8*)(As + row * 64 + (colE ^ ((row & 7) << 3)));
      }
#pragma unroll
      for (int j = 0; j < 4; ++j) {
        int row = wn + j * 16 + (l & 15);
        int colE = c * 32 + (l >> 4) * 8;
        bfr[j] = *(const short8*)(Bs + row * 64 + (colE ^ ((row & 7) << 3)));
      }
#pragma unroll
      for (int i = 0; i < 2; ++i)
#pragma unroll
        for (int j = 0; j < 4; ++j)
          acc[i][j] = mfma_bf16(af[i], bfr[j], acc[i][j]);
    }
    __syncthreads();
  }

#pragma unroll
  for (int i = 0; i < 2; ++i)
#pragma unroll
    for (int j = 0; j < 4; ++j)
#pragma unroll
      for (int r = 0; r < 4; ++r) {
        int m = m0 + wm + i * 16 + (l >> 4) * 4 + r;
        int n = n0 + wn + j * 16 + (l & 15);
        out[(size_t)m * CDIM + n] = acc[i][j][r] + bout[n];
      }
}

// ---------------- flash attention (swapped QK^T, in-register P, KVBLK=128) ----------------
// Champion structure + MFMA row-sum. V-staging delta: each thread gathers the
// PREIMAGE of one contiguous stored 16B block (src chunks at 32c+4g and +16,
// c=m>>2, g=m&3) and writes a single ds_write_b128 at r*VP + 8m -> write banks
// 4(r+m)%32: 8 disjoint 4-bank groups per phase = conflict-free at floor.
// Stored layout bits identical to R16's interleave -> reads and math unchanged.
#define VP 72  // padded+aligned V row stride (elements)
__global__ __launch_bounds__(256) void attn(const bf16* __restrict__ Q,
                                            const bf16* __restrict__ K,
                                            const bf16* __restrict__ VT,
                                            bf16* __restrict__ O) {
  __shared__ bf16 Ks[2][64 * 64];   // 16KB, swizzled (Ks[0] holds Q tile first)
  __shared__ bf16 Vs[2][65 * VP];   // 18.3KB, interleaved + padded + ones row (64)
  int bh = blockIdx.y, q0 = blockIdx.x * 64;
  int tid = threadIdx.x, w = tid >> 6, l = tid & 63;
  int g = l >> 4, qi = l & 15;

  const bf16* Qg = Q + ((size_t)bh * TT + q0) * HD;
  const bf16* Kg = K + (size_t)bh * TT * HD;
  const bf16* Vg = VT + (size_t)bh * TT * HD;  // [64][T]

  // stage Q tile [64][64] into Ks[0] (pre-swizzled source, linear dest)
#pragma unroll
  for (int it = 0; it < 2; ++it) {
    int ci = it * 256 + tid, r = ci >> 3, cc = ci & 7;
    gll16(Qg + (size_t)r * HD + (cc ^ (r & 7)) * 8, &Ks[0][0] + (it * 256 + w * 64) * 8);
  }
  // ones row (row 64) for both V buffers — persists across the loop
  if (tid < 64) {
    bf16 one = __float2bfloat16(1.0f);
    Vs[0][64 * VP + tid] = one;
    Vs[1][64 * VP + tid] = one;
  }
  __syncthreads();
  short8 aq[2];  // Q B-frag: col q = w*16+qi, depth d = c*32 + g*8 .. +8
#pragma unroll
  for (int c = 0; c < 2; ++c) {
    int row = w * 16 + qi;
    int colE = c * 32 + g * 8;
    aq[c] = *(const short8*)(&Ks[0][row * 64 + (colE ^ ((row & 7) << 3))]);
  }
  __syncthreads();  // all waves done reading Q before K overwrites Ks[0]

  // hoisted per-thread staging pointers/offsets
  const bf16* kptr[2];
  const bf16* vptr[2];
  int kdst[2], vdst[2];
#pragma unroll
  for (int it = 0; it < 2; ++it) {
    int ci = it * 256 + tid, r = ci >> 3, cc = ci & 7;
    kptr[it] = Kg + (size_t)r * HD + (cc ^ (r & 7)) * 8;
    // V: thread gathers src chunks o1 = 32(cc>>2)+4(cc&3) and o1+16 for stored
    // block 8*cc of row r
    vptr[it] = Vg + (size_t)r * TT + 32 * (cc >> 2) + 4 * (cc & 3);
    kdst[it] = (it * 256 + w * 64) * 8;
    vdst[it] = r * VP + 8 * cc;
  }

  f32x4 oacc[4] = {};
  f32x4 osum = {};

  for (int kt = 0; kt < TT; kt += 128) {
    // stage both sub-tiles: K via gll16; V via 2x uint2 gather -> one b128 write
    uint2 vlo[2][2], vhi[2][2];
#pragma unroll
    for (int sub = 0; sub < 2; ++sub)
#pragma unroll
      for (int it = 0; it < 2; ++it) {
        gll16(kptr[it] + (size_t)(kt + sub * 64) * HD, &Ks[sub][0] + kdst[it]);
        vlo[sub][it] = *(const uint2*)(vptr[it] + kt + sub * 64);
        vhi[sub][it] = *(const uint2*)(vptr[it] + kt + sub * 64 + 16);
      }
#pragma unroll
    for (int sub = 0; sub < 2; ++sub)
#pragma unroll
      for (int it = 0; it < 2; ++it) {
        uint4 v4;
        v4.x = vlo[sub][it].x; v4.y = vlo[sub][it].y;
        v4.z = vhi[sub][it].x; v4.w = vhi[sub][it].y;
        *(uint4*)(&Vs[sub][vdst[it]]) = v4;
      }
    __syncthreads();

#pragma unroll
    for (int sub = 0; sub < 2; ++sub) {
      // S^T = K Q^T: lane holds S[q=qi][k = 16kn + 4g + r]  (Q pre-scaled)
      f32x4 s[4] = {};
      __builtin_amdgcn_s_setprio(1);
#pragma unroll
      for (int kn = 0; kn < 4; ++kn) {
#pragma unroll
        for (int c = 0; c < 2; ++c) {
          int row = kn * 16 + qi;
          int colE = c * 32 + g * 8;
          short8 kf = *(const short8*)(&Ks[sub][row * 64 + (colE ^ ((row & 7) << 3))]);
          s[kn] = mfma_bf16(kf, aq[c], s[kn]);
        }
      }
      __builtin_amdgcn_s_setprio(0);

      // p = exp2(s) in-register; pack to bf16 pairs
      uint32_t wlo[4], whi[4];
#pragma unroll
      for (int kn = 0; kn < 4; ++kn) {
        float p0 = exp2_fast(s[kn][0]);
        float p1 = exp2_fast(s[kn][1]);
        float p2 = exp2_fast(s[kn][2]);
        float p3 = exp2_fast(s[kn][3]);
        wlo[kn] = pkbf16(p0, p1);
        whi[kn] = pkbf16(p2, p3);
      }

      // O += P V, permuted depth: slot (c,g,j) -> k = 32c + 16*(j>=4) + 4g + (j&3).
      // Interleaved V: the whole B-fragment is one b128 at 32c + 8g.
      // Row 64 (ones) accumulates osum[r] = sum_k P[q=4g+r][k] on the MFMA pipe.
      __builtin_amdgcn_s_setprio(1);
#pragma unroll
      for (int c = 0; c < 2; ++c) {
        union { short8 s8; uint32_t u[4]; } pa;
        pa.u[0] = wlo[2 * c];     pa.u[1] = whi[2 * c];
        pa.u[2] = wlo[2 * c + 1]; pa.u[3] = whi[2 * c + 1];
#pragma unroll
        for (int dn = 0; dn < 4; ++dn) {
          int row = dn * 16 + qi;           // d-row of Vs
          short8 vb = *(const short8*)(&Vs[sub][row * VP + c * 32 + g * 8]);
          oacc[dn] = mfma_bf16(pa.s8, vb, oacc[dn]);
        }
        short8 vones = *(const short8*)(&Vs[sub][64 * VP + c * 32 + g * 8]);
        osum = mfma_bf16(pa.s8, vones, osum);
      }
      __builtin_amdgcn_s_setprio(0);
    }
    __syncthreads();
  }

  // epilogue: oacc row q = 4g+r, col d = dn*16+qi; osum[r] = row-sum for q = 4g+r.
  // O layout [b][t][h*64+d]
  int b = bh >> 4, hh = bh & 15;
#pragma unroll
  for (int r = 0; r < 4; ++r) {
    float inv = 1.0f / osum[r];
    int t = q0 + w * 16 + g * 4 + r;
    bf16* Orow = O + ((size_t)(b * TT + t)) * CDIM + hh * HD;
#pragma unroll
    for (int dn = 0; dn < 4; ++dn)
      Orow[dn * 16 + qi] = __float2bfloat16(oacc[dn][r] * inv);
  }
}

// ---------------- launcher ----------------

extern "C" void kernel_launch(void* const* d_in, const int* in_sizes, int n_in,
                              void* d_out, int out_size, void* d_ws, size_t ws_size,
                              hipStream_t stream) {
  const float* x    = (const float*)d_in[0];
  const float* Wqkv = (const float*)d_in[1];
  const float* Wout = (const float*)d_in[2];
  const float* bout = (const float*)d_in[3];
  float* out = (float*)d_out;

  char* ws = (char*)d_ws;
  bf16* xb     = (bf16*)(ws);                    // 8 MB (reused as O after attn)
  bf16* WqkvT  = (bf16*)(ws + 8388608);          // 6 MB
  bf16* WoutT  = (bf16*)(ws + 14680064);         // 2 MB
  bf16* Qb     = (bf16*)(ws + 16777216);         // 8 MB
  bf16* Kb     = (bf16*)(ws + 25165824);         // 8 MB
  bf16* VTb    = (bf16*)(ws + 41943040);         // 8 MB (written transposed by qkv_gemm)
  float2* cs   = (float2*)(ws + 50331648);       // 512 KB (cos,sin interleaved)
  bf16* Ob     = xb;                             // reuse

  prep<<<6400, 256, 0, stream>>>(x, xb, Wqkv, WqkvT, Wout, WoutT, cs);
  qkv_gemm<<<dim3(24, 64), 256, 0, stream>>>(xb, WqkvT, cs, Qb, Kb, VTb);
  attn<<<dim3(32, 32), 256, 0, stream>>>(Qb, Kb, VTb, Ob);
  out_gemm<<<dim3(8, 64), 256, 0, stream>>>(Ob, WoutT, bout, out);
}

// Round 24
// 118.940 us; speedup vs baseline: 1.0132x; 1.0132x over previous
//
#include <hip/hip_runtime.h>
#include <hip/hip_bf16.h>
#include <cstdint>

#define TT 2048
#define HD 64
#define NH 16
#define CDIM 1024
#define N3 3072
#define BT 4096
#define QSCALE 0.18033688011112042f  // 0.125 * log2(e)

using bf16 = __hip_bfloat16;
typedef __attribute__((ext_vector_type(4))) float f32x4;
typedef __attribute__((ext_vector_type(8))) short short8;
typedef __attribute__((ext_vector_type(8))) __bf16 bf16x8v;

__device__ __forceinline__ short f2bbits(float f) {
  __hip_bfloat16 h = __float2bfloat16(f);
  return __builtin_bit_cast(short, h);
}

__device__ __forceinline__ f32x4 mfma_bf16(short8 a, short8 b, f32x4 c) {
  return __builtin_amdgcn_mfma_f32_16x16x32_bf16(
      __builtin_bit_cast(bf16x8v, a), __builtin_bit_cast(bf16x8v, b), c, 0, 0, 0);
}

__device__ __forceinline__ void gll16(const void* g, void* l) {
  __builtin_amdgcn_global_load_lds(
      (const __attribute__((address_space(1))) void*)g,
      (__attribute__((address_space(3))) void*)l, 16, 0, 0);
}

// v_exp_f32 computes 2^x
__device__ __forceinline__ float exp2_fast(float x) {
  float r;
  asm("v_exp_f32 %0, %1" : "=v"(r) : "v"(x));
  return r;
}

// pack two f32 -> one u32 of 2 bf16 (lo = first arg), RNE
__device__ __forceinline__ uint32_t pkbf16(float lo, float hi) {
  uint32_t lw = (uint32_t)(uint16_t)f2bbits(lo);
  uint32_t hw = (uint32_t)(uint16_t)f2bbits(hi);
  return (hw << 16) | lw;
}

// ---------------- fused prep kernel ----------------
// blocks [0,2048): cvt x -> xb
// blocks [2048,5120): transpose Wqkv [1024][3072] -> WqkvT bf16
// blocks [5120,6144): transpose Wout [1024][1024] -> WoutT bf16
// blocks [6144,6400): rope cos/sin table (float2 interleaved)

__device__ __forceinline__ void transpose_body(const float* __restrict__ in,
                                               bf16* __restrict__ out, int R, int C,
                                               int bx, int by, int tx, int ty,
                                               float (*tile)[33]) {
  int c0 = bx * 32, r0 = by * 32;
#pragma unroll
  for (int i = 0; i < 32; i += 8)
    tile[ty + i][tx] = in[(size_t)(r0 + ty + i) * C + c0 + tx];
  __syncthreads();
#pragma unroll
  for (int i = 0; i < 32; i += 8)
    out[(size_t)(c0 + ty + i) * R + r0 + tx] = __float2bfloat16(tile[tx][ty + i]);
}

__global__ __launch_bounds__(256) void prep(const float* __restrict__ x, bf16* __restrict__ xb,
                                            const float* __restrict__ Wqkv, bf16* __restrict__ WqkvT,
                                            const float* __restrict__ Wout, bf16* __restrict__ WoutT,
                                            float2* __restrict__ cs) {
  __shared__ float tile[32][33];
  int bid = blockIdx.x, tid = threadIdx.x;
  if (bid < 2048) {
    int idx = (bid * 256 + tid) * 8;
    float4 a = *(const float4*)(x + idx);
    float4 b = *(const float4*)(x + idx + 4);
    short8 o;
    o[0] = f2bbits(a.x); o[1] = f2bbits(a.y); o[2] = f2bbits(a.z); o[3] = f2bbits(a.w);
    o[4] = f2bbits(b.x); o[5] = f2bbits(b.y); o[6] = f2bbits(b.z); o[7] = f2bbits(b.w);
    *(short8*)(xb + idx) = o;
  } else if (bid < 5120) {
    int id = bid - 2048;
    transpose_body(Wqkv, WqkvT, CDIM, N3, id % 96, id / 96, tid & 31, tid >> 5, tile);
  } else if (bid < 6144) {
    int id = bid - 5120;
    transpose_body(Wout, WoutT, CDIM, CDIM, id & 31, id >> 5, tid & 31, tid >> 5, tile);
  } else {
    int idx = (bid - 6144) * 256 + tid;  // t*32 + i
    int t = idx >> 5, i = idx & 31;
    double inv = exp(-(double)i / 32.0 * log(10000.0));
    double a = (double)t * inv;
    float2 v; v.x = (float)cos(a); v.y = (float)sin(a);
    cs[idx] = v;
  }
}

// ---------------- GEMM core: C[128x128] = A[128xK] * Bt[128xK]^T ----------------
// BK=64, XOR-swizzled LDS (pre-swizzled global source chunks, linear gll16 dest,
// swizzled ds_read). 256 threads, 4 waves (2x2 of 64x64 sub-tiles).

__device__ __forceinline__ void gemm_core(const bf16* __restrict__ A, const bf16* __restrict__ Bt,
                                          int K, int m0, int n0, f32x4 acc[4][4],
                                          bf16* As, bf16* Bs) {
  int tid = threadIdx.x;
  int w = tid >> 6, l = tid & 63;
  int wm = (w >> 1) * 64, wn = (w & 1) * 64;
  for (int kt = 0; kt < K; kt += 64) {
#pragma unroll
    for (int it = 0; it < 4; ++it) {
      int ci = it * 256 + tid;            // 0..1023 chunk index (16B chunks)
      int r = ci >> 3, cc = ci & 7;
      int sc = cc ^ (r & 7);              // pre-swizzled source chunk
      gll16(A + (size_t)(m0 + r) * K + kt + sc * 8, As + (it * 256 + w * 64) * 8);
      gll16(Bt + (size_t)(n0 + r) * K + kt + sc * 8, Bs + (it * 256 + w * 64) * 8);
    }
    __syncthreads();
#pragma unroll
    for (int c = 0; c < 2; ++c) {
      short8 af[4], bfr[4];
#pragma unroll
      for (int i = 0; i < 4; ++i) {
        int row = wm + i * 16 + (l & 15);
        int colE = c * 32 + (l >> 4) * 8;
        af[i] = *(const short8*)(As + row * 64 + (colE ^ ((row & 7) << 3)));
      }
#pragma unroll
      for (int j = 0; j < 4; ++j) {
        int row = wn + j * 16 + (l & 15);
        int colE = c * 32 + (l >> 4) * 8;
        bfr[j] = *(const short8*)(Bs + row * 64 + (colE ^ ((row & 7) << 3)));
      }
#pragma unroll
      for (int i = 0; i < 4; ++i)
#pragma unroll
        for (int j = 0; j < 4; ++j)
          acc[i][j] = mfma_bf16(af[i], bfr[j], acc[i][j]);
    }
    __syncthreads();
  }
}

// QKV GEMM: x[4096][1024] @ Wqkv, tile 64x128 (BM=64), grid (24,64) = 1536 blocks.
// Q/K: RoPE fused (pair (d,d+32) in-lane), Q pre-scaled by QSCALE.
// V: written DIRECTLY TRANSPOSED to VT [bh][64 d][T t] via LDS bounce (64d x 64t).
__global__ __launch_bounds__(256) void qkv_gemm(const bf16* __restrict__ xb,
                                                const bf16* __restrict__ WqkvT,
                                                const float2* __restrict__ cs,
                                                bf16* __restrict__ Qb, bf16* __restrict__ Kb,
                                                bf16* __restrict__ VTb) {
  __shared__ bf16 Sh[64 * 64 + 128 * 64];   // As (8KB) | Bs (16KB); Sh reused as V bounce
  bf16* As = Sh;
  bf16* Bs = Sh + 64 * 64;
  int m0 = blockIdx.y * 64, n0 = blockIdx.x * 128;
  int tid = threadIdx.x, w = tid >> 6, l = tid & 63;
  int wm = (w >> 1) * 32, wn = (w & 1) * 64;
  f32x4 acc[2][4] = {};

  for (int kt = 0; kt < CDIM; kt += 64) {
    // stage A tile 64x64 (512 chunks) + B tile 128x64 (1024 chunks)
#pragma unroll
    for (int it = 0; it < 2; ++it) {
      int ci = it * 256 + tid, r = ci >> 3, cc = ci & 7;
      int sc = cc ^ (r & 7);
      gll16(xb + (size_t)(m0 + r) * CDIM + kt + sc * 8, As + (it * 256 + w * 64) * 8);
    }
#pragma unroll
    for (int it = 0; it < 4; ++it) {
      int ci = it * 256 + tid, r = ci >> 3, cc = ci & 7;
      int sc = cc ^ (r & 7);
      gll16(WqkvT + (size_t)(n0 + r) * CDIM + kt + sc * 8, Bs + (it * 256 + w * 64) * 8);
    }
    __syncthreads();
#pragma unroll
    for (int c = 0; c < 2; ++c) {
      short8 af[2], bfr[4];
#pragma unroll
      for (int i = 0; i < 2; ++i) {
        int row = wm + i * 16 + (l & 15);
        int colE = c * 32 + (l >> 4) * 8;
        af[i] = *(const short8*)(As + row * 64 + (colE ^ ((row & 7) << 3)));
      }
#pragma unroll
      for (int j = 0; j < 4; ++j) {
        int row = wn + j * 16 + (l & 15);
        int colE = c * 32 + (l >> 4) * 8;
        bfr[j] = *(const short8*)(Bs + row * 64 + (colE ^ ((row & 7) << 3)));
      }
#pragma unroll
      for (int i = 0; i < 2; ++i)
#pragma unroll
        for (int j = 0; j < 4; ++j)
          acc[i][j] = mfma_bf16(af[i], bfr[j], acc[i][j]);
    }
    __syncthreads();
  }

  int which = n0 >> 10;                       // 0=Q 1=K 2=V
  if (which < 2) {
    int h = ((n0 + wn) & 1023) >> 6;          // head (wn is 0 or 64 -> full head per wave)
    bf16* Out = which == 0 ? Qb : Kb;
    float sc = (which == 0) ? QSCALE : 1.0f;
    // RoPE: pair (d, d+32) lives in (acc[i][j], acc[i][j+2]) of the same lane
#pragma unroll
    for (int i = 0; i < 2; ++i)
#pragma unroll
      for (int r = 0; r < 4; ++r) {
        int m = m0 + wm + i * 16 + (l >> 4) * 4 + r;
        int b = m >> 11, t = m & 2047;
        size_t base = (((size_t)(b * NH + h)) * TT + t) * HD;
#pragma unroll
        for (int j = 0; j < 2; ++j) {
          int ii = j * 16 + (l & 15);         // d in [0,32)
          float2 v = cs[t * 32 + ii];
          float x1 = acc[i][j][r], x2 = acc[i][j + 2][r];
          Out[base + ii]      = __float2bfloat16((x1 * v.x - x2 * v.y) * sc);
          Out[base + ii + 32] = __float2bfloat16((x2 * v.x + x1 * v.y) * sc);
        }
      }
  } else {
    // V: transpose through LDS bounce [64 dloc][pitch 72] (64 t), then coalesced
    // stores to VTb[bh][d][t0..t0+63]. Two passes, one head (64 d) each.
    const int BP = 72;                        // 16B-aligned pitch (144B rows)
    int hb = (n0 & 1023) >> 6;                // first of the 2 heads in this block
    int b = m0 >> 11, t0 = m0 & 2047;
#pragma unroll
    for (int p = 0; p < 2; ++p) {
      if ((w & 1) == p) {                     // waves whose wn == 64*p hold this head
#pragma unroll
        for (int i = 0; i < 2; ++i)
#pragma unroll
          for (int j = 0; j < 4; ++j)
#pragma unroll
            for (int r = 0; r < 4; ++r) {
              int dloc = j * 16 + (l & 15);
              int mloc = wm + i * 16 + (l >> 4) * 4 + r;
              Sh[dloc * BP + mloc] = __float2bfloat16(acc[i][j][r]);
            }
      }
      __syncthreads();
      {
        int dloc = tid >> 2, tch = (tid & 3) * 16;
        bf16* dst = VTb + (((size_t)(b * NH + hb + p)) * HD + dloc) * TT + t0 + tch;
        const bf16* srcb = Sh + dloc * BP + tch;
#pragma unroll
        for (int k2 = 0; k2 < 2; ++k2)
          *(uint4*)(dst + k2 * 8) = *(const uint4*)(srcb + k2 * 8);
      }
      __syncthreads();
    }
  }
}

// Out GEMM: O[4096][1024] @ Wout + bout -> out fp32.
// Tile 64x128 (BM=64), grid (8,64) = 512 blocks = 2 blocks/CU.
__global__ __launch_bounds__(256) void out_gemm(const bf16* __restrict__ Ob,
                                                const bf16* __restrict__ WoutT,
                                                const float* __restrict__ bout,
                                                float* __restrict__ out) {
  __shared__ bf16 As[64 * 64];    // 8KB
  __shared__ bf16 Bs[128 * 64];   // 16KB
  int m0 = blockIdx.y * 64, n0 = blockIdx.x * 128;
  int tid = threadIdx.x, w = tid >> 6, l = tid & 63;
  int wm = (w >> 1) * 32, wn = (w & 1) * 64;
  f32x4 acc[2][4] = {};

  for (int kt = 0; kt < CDIM; kt += 64) {
#pragma unroll
    for (int it = 0; it < 2; ++it) {
      int ci = it * 256 + tid, r = ci >> 3, cc = ci & 7;
      int sc = cc ^ (r & 7);
      gll16(Ob + (size_t)(m0 + r) * CDIM + kt + sc * 8, As + (it * 256 + w * 64) * 8);
    }
#pragma unroll
    for (int it = 0; it < 4; ++it) {
      int ci = it * 256 + tid, r = ci >> 3, cc = ci & 7;
      int sc = cc ^ (r & 7);
      gll16(WoutT + (size_t)(n0 + r) * CDIM + kt + sc * 8, Bs + (it * 256 + w * 64) * 8);
    }
    __syncthreads();
#pragma unroll
    for (int c = 0; c < 2; ++c) {
      short8 af[2], bfr[4];
#pragma unroll
      for (int i = 0; i < 2; ++i) {
        int row = wm + i * 16 + (l & 15);
        int colE = c * 32 + (l >> 4) * 8;
        af[i] = *(const short8*)(As + row * 64 + (colE ^ ((row & 7) << 3)));
      }
#pragma unroll
      for (int j = 0; j < 4; ++j) {
        int row = wn + j * 16 + (l & 15);
        int colE = c * 32 + (l >> 4) * 8;
        bfr[j] = *(const short8*)(Bs + row * 64 + (colE ^ ((row & 7) << 3)));
      }
#pragma unroll
      for (int i = 0; i < 2; ++i)
#pragma unroll
        for (int j = 0; j < 4; ++j)
          acc[i][j] = mfma_bf16(af[i], bfr[j], acc[i][j]);
    }
    __syncthreads();
  }

#pragma unroll
  for (int i = 0; i < 2; ++i)
#pragma unroll
    for (int j = 0; j < 4; ++j)
#pragma unroll
      for (int r = 0; r < 4; ++r) {
        int m = m0 + wm + i * 16 + (l >> 4) * 4 + r;
        int n = n0 + wn + j * 16 + (l & 15);
        out[(size_t)m * CDIM + n] = acc[i][j][r] + bout[n];
      }
}

// ---------------- flash attention (swapped QK^T, in-register P, KVBLK=128) ----------------
// Champion structure + MFMA row-sum (65th all-ones V row -> osum on matrix pipe).
#define VP 72  // padded+aligned V row stride (elements)
__global__ __launch_bounds__(256) void attn(const bf16* __restrict__ Q,
                                            const bf16* __restrict__ K,
                                            const bf16* __restrict__ VT,
                                            bf16* __restrict__ O) {
  __shared__ bf16 Ks[2][64 * 64];   // 16KB, swizzled (Ks[0] holds Q tile first)
  __shared__ bf16 Vs[2][65 * VP];   // 18.3KB, interleaved + padded + ones row (64)
  int bh = blockIdx.y, q0 = blockIdx.x * 64;
  int tid = threadIdx.x, w = tid >> 6, l = tid & 63;
  int g = l >> 4, qi = l & 15;

  const bf16* Qg = Q + ((size_t)bh * TT + q0) * HD;
  const bf16* Kg = K + (size_t)bh * TT * HD;
  const bf16* Vg = VT + (size_t)bh * TT * HD;  // [64][T]

  // stage Q tile [64][64] into Ks[0] (pre-swizzled source, linear dest)
#pragma unroll
  for (int it = 0; it < 2; ++it) {
    int ci = it * 256 + tid, r = ci >> 3, cc = ci & 7;
    gll16(Qg + (size_t)r * HD + (cc ^ (r & 7)) * 8, &Ks[0][0] + (it * 256 + w * 64) * 8);
  }
  // ones row (row 64) for both V buffers — persists across the loop
  if (tid < 64) {
    bf16 one = __float2bfloat16(1.0f);
    Vs[0][64 * VP + tid] = one;
    Vs[1][64 * VP + tid] = one;
  }
  __syncthreads();
  short8 aq[2];  // Q B-frag: col q = w*16+qi, depth d = c*32 + g*8 .. +8
#pragma unroll
  for (int c = 0; c < 2; ++c) {
    int row = w * 16 + qi;
    int colE = c * 32 + g * 8;
    aq[c] = *(const short8*)(&Ks[0][row * 64 + (colE ^ ((row & 7) << 3))]);
  }
  __syncthreads();  // all waves done reading Q before K overwrites Ks[0]

  // hoisted per-thread staging pointers/offsets
  const bf16* kptr[2];
  const bf16* vptr[2];
  int kdst[2], vdst[2];
#pragma unroll
  for (int it = 0; it < 2; ++it) {
    int ci = it * 256 + tid, r = ci >> 3, cc = ci & 7;
    kptr[it] = Kg + (size_t)r * HD + (cc ^ (r & 7)) * 8;
    vptr[it] = Vg + (size_t)r * TT + cc * 8;
    kdst[it] = (it * 256 + w * 64) * 8;
    vdst[it] = r * VP + 32 * (cc >> 2) + 16 * (cc & 1) + 4 * ((cc >> 1) & 1);
  }

  f32x4 oacc[4] = {};
  f32x4 osum = {};

  for (int kt = 0; kt < TT; kt += 128) {
    // stage both sub-tiles: K via gll16; V via reg -> interleaved LDS (rows 0-63)
    uint4 vr[2][2];
#pragma unroll
    for (int sub = 0; sub < 2; ++sub)
#pragma unroll
      for (int it = 0; it < 2; ++it) {
        gll16(kptr[it] + (size_t)(kt + sub * 64) * HD, &Ks[sub][0] + kdst[it]);
        vr[sub][it] = *(const uint4*)(vptr[it] + kt + sub * 64);
      }
#pragma unroll
    for (int sub = 0; sub < 2; ++sub)
#pragma unroll
      for (int it = 0; it < 2; ++it) {
        uint2 lo; lo.x = vr[sub][it].x; lo.y = vr[sub][it].y;
        uint2 hi; hi.x = vr[sub][it].z; hi.y = vr[sub][it].w;
        *(uint2*)(&Vs[sub][vdst[it]]) = lo;
        *(uint2*)(&Vs[sub][vdst[it] + 8]) = hi;
      }
    __syncthreads();

#pragma unroll
    for (int sub = 0; sub < 2; ++sub) {
      // S^T = K Q^T: lane holds S[q=qi][k = 16kn + 4g + r]  (Q pre-scaled)
      f32x4 s[4] = {};
      __builtin_amdgcn_s_setprio(1);
#pragma unroll
      for (int kn = 0; kn < 4; ++kn) {
#pragma unroll
        for (int c = 0; c < 2; ++c) {
          int row = kn * 16 + qi;
          int colE = c * 32 + g * 8;
          short8 kf = *(const short8*)(&Ks[sub][row * 64 + (colE ^ ((row & 7) << 3))]);
          s[kn] = mfma_bf16(kf, aq[c], s[kn]);
        }
      }
      __builtin_amdgcn_s_setprio(0);

      // p = exp2(s) in-register; pack to bf16 pairs
      uint32_t wlo[4], whi[4];
#pragma unroll
      for (int kn = 0; kn < 4; ++kn) {
        float p0 = exp2_fast(s[kn][0]);
        float p1 = exp2_fast(s[kn][1]);
        float p2 = exp2_fast(s[kn][2]);
        float p3 = exp2_fast(s[kn][3]);
        wlo[kn] = pkbf16(p0, p1);
        whi[kn] = pkbf16(p2, p3);
      }

      // O += P V, permuted depth: slot (c,g,j) -> k = 32c + 16*(j>=4) + 4g + (j&3).
      // Interleaved V: the whole B-fragment is one b128 at 32c + 8g.
      // Row 64 (ones) accumulates osum[r] = sum_k P[q=4g+r][k] on the MFMA pipe.
      __builtin_amdgcn_s_setprio(1);
#pragma unroll
      for (int c = 0; c < 2; ++c) {
        union { short8 s8; uint32_t u[4]; } pa;
        pa.u[0] = wlo[2 * c];     pa.u[1] = whi[2 * c];
        pa.u[2] = wlo[2 * c + 1]; pa.u[3] = whi[2 * c + 1];
#pragma unroll
        for (int dn = 0; dn < 4; ++dn) {
          int row = dn * 16 + qi;           // d-row of Vs
          short8 vb = *(const short8*)(&Vs[sub][row * VP + c * 32 + g * 8]);
          oacc[dn] = mfma_bf16(pa.s8, vb, oacc[dn]);
        }
        short8 vones = *(const short8*)(&Vs[sub][64 * VP + c * 32 + g * 8]);
        osum = mfma_bf16(pa.s8, vones, osum);
      }
      __builtin_amdgcn_s_setprio(0);
    }
    __syncthreads();
  }

  // epilogue: oacc row q = 4g+r, col d = dn*16+qi; osum[r] = row-sum for q = 4g+r.
  // O layout [b][t][h*64+d]
  int b = bh >> 4, hh = bh & 15;
#pragma unroll
  for (int r = 0; r < 4; ++r) {
    float inv = 1.0f / osum[r];
    int t = q0 + w * 16 + g * 4 + r;
    bf16* Orow = O + ((size_t)(b * TT + t)) * CDIM + hh * HD;
#pragma unroll
    for (int dn = 0; dn < 4; ++dn)
      Orow[dn * 16 + qi] = __float2bfloat16(oacc[dn][r] * inv);
  }
}

// ---------------- launcher ----------------

extern "C" void kernel_launch(void* const* d_in, const int* in_sizes, int n_in,
                              void* d_out, int out_size, void* d_ws, size_t ws_size,
                              hipStream_t stream) {
  const float* x    = (const float*)d_in[0];
  const float* Wqkv = (const float*)d_in[1];
  const float* Wout = (const float*)d_in[2];
  const float* bout = (const float*)d_in[3];
  float* out = (float*)d_out;

  char* ws = (char*)d_ws;
  bf16* xb     = (bf16*)(ws);                    // 8 MB (reused as O after attn)
  bf16* WqkvT  = (bf16*)(ws + 8388608);          // 6 MB
  bf16* WoutT  = (bf16*)(ws + 14680064);         // 2 MB
  bf16* Qb     = (bf16*)(ws + 16777216);         // 8 MB
  bf16* Kb     = (bf16*)(ws + 25165824);         // 8 MB
  bf16* VTb    = (bf16*)(ws + 41943040);         // 8 MB (written transposed by qkv_gemm)
  float2* cs   = (float2*)(ws + 50331648);       // 512 KB (cos,sin interleaved)
  bf16* Ob     = xb;                             // reuse

  prep<<<6400, 256, 0, stream>>>(x, xb, Wqkv, WqkvT, Wout, WoutT, cs);
  qkv_gemm<<<dim3(24, 64), 256, 0, stream>>>(xb, WqkvT, cs, Qb, Kb, VTb);
  attn<<<dim3(32, 32), 256, 0, stream>>>(Qb, Kb, VTb, Ob);
  out_gemm<<<dim3(8, 64), 256, 0, stream>>>(Ob, WoutT, bout, out);
}